// Round 4
// baseline (229.460 us; speedup 1.0000x reference)
//
#include <hip/hip_runtime.h>
#include <math.h>

#define B_ 4096
#define Q_ 1024
#define KD 256
#define N_ 16384
#define F_ 512

typedef __attribute__((ext_vector_type(8))) short bhalf8;
typedef __attribute__((ext_vector_type(4))) float f32x4;
typedef __attribute__((ext_vector_type(16))) float f32x16;

static __device__ __forceinline__ unsigned short f2bf(float f) {
  unsigned int u = __builtin_bit_cast(unsigned int, f);
  unsigned int r = (u + 0x7fffu + ((u >> 16) & 1u)) >> 16;
  return (unsigned short)r;
}
static __device__ __forceinline__ unsigned umaxu(unsigned a, unsigned b) { return a > b ? a : b; }
static __device__ __forceinline__ unsigned uminu(unsigned a, unsigned b) { return a < b ? a : b; }

// ---------------------------------------------------------------------------
// k_prep: fused (a) keys fp32->bf16 convert (blocks [0,2048)) and
// (b) qproj GEMM q = ph@Wq + bq in fp32 + bf16 copy (blocks [2048,2304)).
// The streaming convert overlaps the compute-bound qproj.
// ---------------------------------------------------------------------------
__global__ __launch_bounds__(256)
void k_prep(const float* __restrict__ ph, const float* __restrict__ Wq,
            const float* __restrict__ bq, const float* __restrict__ keys,
            float* __restrict__ q, unsigned short* __restrict__ qbf,
            unsigned short* __restrict__ kbf) {
  __shared__ float As[16][64];  // [k][r]
  __shared__ float Ws[16][64];  // [k][c]
  const int tid = threadIdx.x;
  const int bid = blockIdx.x;

  if (bid < 2048) {  // ---- convert keys: 8 elems/thread
    const size_t base = ((size_t)bid * 256 + tid) * 8;
    const float4 x = *reinterpret_cast<const float4*>(&keys[base]);
    const float4 y = *reinterpret_cast<const float4*>(&keys[base + 4]);
    bhalf8 o;
    o[0] = (short)f2bf(x.x); o[1] = (short)f2bf(x.y);
    o[2] = (short)f2bf(x.z); o[3] = (short)f2bf(x.w);
    o[4] = (short)f2bf(y.x); o[5] = (short)f2bf(y.y);
    o[6] = (short)f2bf(y.z); o[7] = (short)f2bf(y.w);
    *reinterpret_cast<bhalf8*>(&kbf[base]) = o;
    return;
  }

  // ---- qproj: 4 c-tiles x 64 r-tiles
  const int qb = bid - 2048;
  const int tx = tid & 15, ty = tid >> 4;
  const int c0 = (qb & 3) * 64, r0 = (qb >> 2) * 64;
  float acc[4][4] = {};
  for (int kt = 0; kt < Q_; kt += 16) {
    {
      const int r = tid >> 2;
      const int k4 = (tid & 3) * 4;
      const float4 v = *reinterpret_cast<const float4*>(&ph[(size_t)(r0 + r) * Q_ + kt + k4]);
      As[k4 + 0][r] = v.x; As[k4 + 1][r] = v.y;
      As[k4 + 2][r] = v.z; As[k4 + 3][r] = v.w;
    }
    {
      const int kq = tid >> 4;
      const int c4 = (tid & 15) * 4;
      *reinterpret_cast<float4*>(&Ws[kq][c4]) =
          *reinterpret_cast<const float4*>(&Wq[(size_t)(kt + kq) * KD + c0 + c4]);
    }
    __syncthreads();
#pragma unroll
    for (int k = 0; k < 16; ++k) {
      const float4 a = *reinterpret_cast<const float4*>(&As[k][ty * 4]);
      const float4 b = *reinterpret_cast<const float4*>(&Ws[k][tx * 4]);
      acc[0][0] = fmaf(a.x, b.x, acc[0][0]); acc[0][1] = fmaf(a.x, b.y, acc[0][1]);
      acc[0][2] = fmaf(a.x, b.z, acc[0][2]); acc[0][3] = fmaf(a.x, b.w, acc[0][3]);
      acc[1][0] = fmaf(a.y, b.x, acc[1][0]); acc[1][1] = fmaf(a.y, b.y, acc[1][1]);
      acc[1][2] = fmaf(a.y, b.z, acc[1][2]); acc[1][3] = fmaf(a.y, b.w, acc[1][3]);
      acc[2][0] = fmaf(a.z, b.x, acc[2][0]); acc[2][1] = fmaf(a.z, b.y, acc[2][1]);
      acc[2][2] = fmaf(a.z, b.z, acc[2][2]); acc[2][3] = fmaf(a.z, b.w, acc[2][3]);
      acc[3][0] = fmaf(a.w, b.x, acc[3][0]); acc[3][1] = fmaf(a.w, b.y, acc[3][1]);
      acc[3][2] = fmaf(a.w, b.z, acc[3][2]); acc[3][3] = fmaf(a.w, b.w, acc[3][3]);
    }
    __syncthreads();
  }
#pragma unroll
  for (int i = 0; i < 4; ++i) {
    const int r = r0 + ty * 4 + i;
    const int c = c0 + tx * 4;
    float4 v;
    v.x = acc[i][0] + bq[c + 0]; v.y = acc[i][1] + bq[c + 1];
    v.z = acc[i][2] + bq[c + 2]; v.w = acc[i][3] + bq[c + 3];
    *reinterpret_cast<float4*>(&q[(size_t)r * KD + c]) = v;
    ushort4 bv;
    bv.x = f2bf(v.x); bv.y = f2bf(v.y); bv.z = f2bf(v.z); bv.w = f2bf(v.w);
    *reinterpret_cast<ushort4*>(&qbf[(size_t)r * KD + c]) = bv;
  }
}

// ---------------------------------------------------------------------------
// k_scores_mfma: 32x32x16 MFMA + branchless packed top-3 per lane, PLUS
// interleaved zeroing of this block's 256KB slice of the alpha output
// (hides the 268MB fill under compute; HBM was ~1% busy here).
// Block (bc,br): rows [br*64,+64) x cols [bc*1024,+1024).
// ---------------------------------------------------------------------------
__global__ __launch_bounds__(256, 3)
void k_scores_mfma(const unsigned short* __restrict__ qbf,
                   const unsigned short* __restrict__ kbf,
                   unsigned* __restrict__ candP, float* __restrict__ outAlpha) {
  __shared__ __align__(16) char lds[32768];   // 2 x 16KB key tiles (64c x 128k)
  __shared__ unsigned mbuf[64 * 12];
  const int tid = threadIdx.x;
  const int wave = tid >> 6, lane = tid & 63;
  const int l31 = lane & 31, lhi = lane >> 5;
  const int rh = wave >> 1, ch = wave & 1;
  const int bc = blockIdx.x, br = blockIdx.y;
  const int row0 = br * 64;
  const int m_row = row0 + rh * 32 + l31;

  // alpha-zero slice for this block: 256KB = 32 phases x 2 float4-stores/thread
  float4* zb = reinterpret_cast<float4*>(
      (char*)outAlpha + (size_t)(br * 16 + bc) * 262144);
  const float4 z4 = {0.f, 0.f, 0.f, 0.f};

  // ---- q fragments (B-operand): qf[kt] = qbf[m_row][kt*16 + lhi*8 ..+8)
  bhalf8 qf[16];
#pragma unroll
  for (int kt = 0; kt < 16; ++kt)
    qf[kt] = *reinterpret_cast<const bhalf8*>(&qbf[(size_t)m_row * KD + kt * 16 + lhi * 8]);

  auto stage = [&](int bi, int u) {
    const int t = u >> 1, kh = u & 1;
#pragma unroll
    for (int i = 0; i < 4; ++i) {
      const int D = i * 4096 + tid * 16;
      const int colt = D >> 8;                 // 0..63
      const int kb = D & 255;
      const int kbs = kb ^ ((colt & 15) << 4);
      const char* src = (const char*)kbf +
          ((size_t)(bc * 1024 + t * 64 + colt) * 512 + kh * 256 + kbs);
      __builtin_amdgcn_global_load_lds(
          (const __attribute__((address_space(1))) unsigned int*)src,
          (__attribute__((address_space(3))) unsigned int*)(lds + bi * 16384 + D),
          16, 0, 0);
    }
  };

  unsigned P1 = 0u, P2 = 0u, P3 = 0u;   // packed top-3, descending
  const int acol = ch * 32 + l31;       // col within 64-col tile (A-operand row)
  const int swz = (acol & 15) << 4;
  const int kofs = lhi * 16;            // A k-offset bytes (8 bf16)

  stage(0, 0);
  __syncthreads();

  int buf = 0;
  for (int t = 0; t < 16; ++t) {
    f32x16 acc = {};
#pragma unroll
    for (int kh = 0; kh < 2; ++kh) {
      const int u = t * 2 + kh;
      if (u < 31) stage(buf ^ 1, u + 1);
      // interleaved alpha zeroing: 2 stores/thread/phase, drains at barrier
      zb[u * 512 + tid] = z4;
      zb[u * 512 + 256 + tid] = z4;
      const char* kb = lds + buf * 16384 + acol * 256;
#pragma unroll
      for (int kt = 0; kt < 8; ++kt) {
        const bhalf8 af = *reinterpret_cast<const bhalf8*>(kb + ((kt * 32 + kofs) ^ swz));
        acc = __builtin_amdgcn_mfma_f32_32x32x16_bf16(af, qf[kh * 8 + kt], acc, 0, 0, 0);
      }
      if (kh == 1) {
        // fold 16 cols of this row into packed top-3 (branchless)
        const int cb = t * 64 + ch * 32 + lhi * 4;
#pragma unroll
        for (int r = 0; r < 16; ++r) {
          const int rofs = (r & 3) + 8 * (r >> 2);
          const unsigned p =
              (__builtin_bit_cast(unsigned, acc[r] + 512.f) & 0xFFFFF800u) |
              (unsigned)(cb + rofs);
          const unsigned w1 = uminu(P1, p); P1 = umaxu(P1, p);
          const unsigned w2 = uminu(P2, w1); P2 = umaxu(P2, w1);
          P3 = umaxu(P3, w2);
        }
      }
      __syncthreads();   // prefetch tile ready (vmcnt drain) + safe to overwrite
      buf ^= 1;
    }
  }

  // ---- block merge: per row 4 slots x 3 -> top-4 -> global candP
  {
    const int mrow = rh * 32 + l31;
    const int slot = ch * 2 + lhi;
    mbuf[mrow * 12 + slot * 3 + 0] = P1;
    mbuf[mrow * 12 + slot * 3 + 1] = P2;
    mbuf[mrow * 12 + slot * 3 + 2] = P3;
  }
  __syncthreads();
  if (tid < 64) {
    unsigned T1 = 0u, T2 = 0u, T3 = 0u, T4 = 0u;
#pragma unroll
    for (int j = 0; j < 12; ++j) {
      const unsigned p = mbuf[tid * 12 + j];
      const unsigned w1 = uminu(T1, p); T1 = umaxu(T1, p);
      const unsigned w2 = uminu(T2, w1); T2 = umaxu(T2, w1);
      const unsigned w3 = uminu(T3, w2); T3 = umaxu(T3, w2);
      T4 = umaxu(T4, w3);
    }
    const size_t o = (size_t)(row0 + tid) * 64 + bc * 4;
    candP[o + 0] = T1; candP[o + 1] = T2; candP[o + 2] = T3; candP[o + 3] = T4;
  }
}

// ---------------------------------------------------------------------------
// k_finalize: one block per row (alpha row already zeroed by k_scores_mfma).
// Top-8 of 64 packed candidates, exact fp32 rescore, top-2 -> softmax ->
// scatter alpha + emb mix * sigmoid(ph·Wb+bb).
// ---------------------------------------------------------------------------
__global__ __launch_bounds__(256)
void k_finalize(const float* __restrict__ q, const float* __restrict__ keys,
                const float* __restrict__ ph, const float* __restrict__ Wb,
                const float* __restrict__ bb, const float* __restrict__ embs,
                const unsigned* __restrict__ candP,
                float* __restrict__ outEmb, float* __restrict__ outAlpha) {
  __shared__ float red[4];
  __shared__ int   topIdx[8];
  __shared__ float resc[8];
  __shared__ float sParam[3];  // a1, a2, beta
  __shared__ int   sIdx[2];
  const int tid = threadIdx.x;
  const int wave = tid >> 6, lane = tid & 63;
  const int row = blockIdx.x;
  float* arow = outAlpha + (size_t)row * N_;

  // Phase B: beta partial sums.
  {
    const float4 a = *reinterpret_cast<const float4*>(&ph[(size_t)row * Q_ + tid * 4]);
    const float4 w = *reinterpret_cast<const float4*>(&Wb[tid * 4]);
    float s = a.x * w.x + a.y * w.y + a.z * w.z + a.w * w.w;
#pragma unroll
    for (int m = 32; m >= 1; m >>= 1) s += __shfl_xor(s, m);
    if (lane == 0) red[wave] = s;
  }

  // Phase C (wave 0): top-8 of 64 packed candidates by repeated wave-max.
  if (wave == 0) {
    unsigned p = candP[(size_t)row * 64 + lane];
    const int mycol = (lane >> 2) * 1024 + (int)(p & 0x7FFu);
#pragma unroll
    for (int it = 0; it < 8; ++it) {
      unsigned mx = p;
#pragma unroll
      for (int m = 32; m >= 1; m >>= 1) {
        const unsigned o = (unsigned)__shfl_xor((int)mx, m);
        mx = mx > o ? mx : o;
      }
      const unsigned long long bal = __ballot(p == mx);
      const int src = __ffsll((unsigned long long)bal) - 1;
      if (lane == src) { topIdx[it] = mycol; p = 0u; }
    }
  }
  __syncthreads();

  // Phase D: exact fp32 rescore of the 8 candidates; wave w does 2.
  {
#pragma unroll
    for (int h = 0; h < 2; ++h) {
      const int cnd = topIdx[wave * 2 + h];
      const float4 qv = *reinterpret_cast<const float4*>(&q[(size_t)row * KD + lane * 4]);
      const float4 kv = *reinterpret_cast<const float4*>(&keys[(size_t)cnd * KD + lane * 4]);
      float s = qv.x * kv.x + qv.y * kv.y + qv.z * kv.z + qv.w * kv.w;
#pragma unroll
      for (int m = 32; m >= 1; m >>= 1) s += __shfl_xor(s, m);
      if (lane == 0) resc[wave * 2 + h] = s * 0.0625f;
    }
  }
  __syncthreads();

  // Phase E (thread 0): top-2 of rescored (tie -> lower index), softmax, beta.
  if (tid == 0) {
    float w1 = -INFINITY, w2 = -INFINITY; int j1 = 0x7fffffff, j2 = 0x7fffffff;
#pragma unroll
    for (int c = 0; c < 8; ++c) {
      const float v = resc[c]; const int x = topIdx[c];
      const bool beat1 = (v > w1) || (v == w1 && x < j1);
      const bool beat2 = (v > w2) || (v == w2 && x < j2);
      if (beat1) { w2 = w1; j2 = j1; w1 = v; j1 = x; }
      else if (beat2) { w2 = v; j2 = x; }
    }
    const float t = expf(w2 - w1);
    const float inv = 1.f / (1.f + t);
    const float bsum = red[0] + red[1] + red[2] + red[3] + bb[0];
    sParam[0] = inv; sParam[1] = t * inv;
    sParam[2] = 1.f / (1.f + expf(-bsum));
    sIdx[0] = j1; sIdx[1] = j2;
  }
  __syncthreads();

  // Phase F: scatter alpha and emb mix.
  const float a1 = sParam[0], a2 = sParam[1], beta = sParam[2];
  const int j1 = sIdx[0], j2 = sIdx[1];
  if (tid == 0) { arow[j1] = a1; arow[j2] = a2; }
  if (tid < 128) {
    const int f = tid * 4;
    const float4 e1 = *reinterpret_cast<const float4*>(&embs[(size_t)j1 * F_ + f]);
    const float4 e2 = *reinterpret_cast<const float4*>(&embs[(size_t)j2 * F_ + f]);
    float4 o;
    o.x = beta * (a1 * e1.x + a2 * e2.x);
    o.y = beta * (a1 * e1.y + a2 * e2.y);
    o.z = beta * (a1 * e1.z + a2 * e2.z);
    o.w = beta * (a1 * e1.w + a2 * e2.w);
    *reinterpret_cast<float4*>(&outEmb[(size_t)row * F_ + f]) = o;
  }
}

// ---------------------------------------------------------------------------
extern "C" void kernel_launch(void* const* d_in, const int* in_sizes, int n_in,
                              void* d_out, int out_size, void* d_ws, size_t ws_size,
                              hipStream_t stream) {
  const float* ph   = (const float*)d_in[0];
  const float* keys = (const float*)d_in[1];
  const float* embs = (const float*)d_in[2];
  const float* Wq   = (const float*)d_in[3];
  const float* bq   = (const float*)d_in[4];
  const float* Wb   = (const float*)d_in[5];
  const float* bb   = (const float*)d_in[6];

  float* outEmb   = (float*)d_out;
  float* outAlpha = outEmb + (size_t)B_ * F_;

  // workspace (~15 MB)
  float*          q     = (float*)d_ws;                             // 4MB
  unsigned short* qbf   = (unsigned short*)(q + (size_t)B_ * KD);   // 2MB
  unsigned short* kbf   = qbf + (size_t)B_ * KD;                    // 8MB
  unsigned*       candP = (unsigned*)(kbf + (size_t)N_ * KD);       // 1MB

  k_prep<<<2304, 256, 0, stream>>>(ph, Wq, bq, keys, q, qbf, kbf);
  k_scores_mfma<<<dim3(16, 64), 256, 0, stream>>>(qbf, kbf, candP, outAlpha);
  k_finalize<<<B_, 256, 0, stream>>>(q, keys, ph, Wb, bb, embs, candP,
                                     outEmb, outAlpha);
}

// Round 5
// 150.895 us; speedup vs baseline: 1.5207x; 1.5207x over previous
//
#include <hip/hip_runtime.h>
#include <math.h>

#define B_ 4096
#define Q_ 1024
#define KD 256
#define N_ 16384
#define F_ 512

typedef __attribute__((ext_vector_type(8))) short bhalf8;
typedef __attribute__((ext_vector_type(4))) float f32x4;
typedef __attribute__((ext_vector_type(16))) float f32x16;

static __device__ __forceinline__ unsigned short f2bf(float f) {
  unsigned int u = __builtin_bit_cast(unsigned int, f);
  unsigned int r = (u + 0x7fffu + ((u >> 16) & 1u)) >> 16;
  return (unsigned short)r;
}
static __device__ __forceinline__ unsigned umaxu(unsigned a, unsigned b) { return a > b ? a : b; }
static __device__ __forceinline__ unsigned uminu(unsigned a, unsigned b) { return a < b ? a : b; }

// ---------------------------------------------------------------------------
// k_convert_keys: keys fp32 -> bf16 (RNE), 8 elems/thread. Standalone again
// (round-4 fusion with qproj was a latency-bound regression).
// ---------------------------------------------------------------------------
__global__ __launch_bounds__(256)
void k_convert_keys(const float* __restrict__ keys, unsigned short* __restrict__ kbf) {
  const size_t base = ((size_t)blockIdx.x * 256 + threadIdx.x) * 8;
  const float4 x = *reinterpret_cast<const float4*>(&keys[base]);
  const float4 y = *reinterpret_cast<const float4*>(&keys[base + 4]);
  bhalf8 o;
  o[0] = (short)f2bf(x.x); o[1] = (short)f2bf(x.y);
  o[2] = (short)f2bf(x.z); o[3] = (short)f2bf(x.w);
  o[4] = (short)f2bf(y.x); o[5] = (short)f2bf(y.y);
  o[6] = (short)f2bf(y.z); o[7] = (short)f2bf(y.w);
  *reinterpret_cast<bhalf8*>(&kbf[base]) = o;
}

// ---------------------------------------------------------------------------
// k_qproj (v2): q = ph@Wq + bq exact fp32, + bf16 copy. 64-deep K-chunks:
// ONE barrier per 64 k-steps (was 2 per 16 -> latency-bound at 1 blk/CU).
// A-tile (ph, needs [k][r] transpose) register-staged; W-tile (already [k][c])
// via global_load_lds. Double-buffered 64KB LDS. grid (4,64), block 256,
// 4x4 register tile. VALU floor at 1 wave/SIMD: ~14us chip-wide.
// ---------------------------------------------------------------------------
__global__ __launch_bounds__(256)
void k_qproj(const float* __restrict__ ph, const float* __restrict__ Wq,
             const float* __restrict__ bq, float* __restrict__ q,
             unsigned short* __restrict__ qbf) {
  __shared__ __align__(16) float As[2][64][64];  // [buf][k][r] 16KB each
  __shared__ __align__(16) float Ws[2][64][64];  // [buf][k][c] 16KB each
  const int tid = threadIdx.x;
  const int tx = tid & 15, ty = tid >> 4;
  const int c0 = blockIdx.x * 64, r0 = blockIdx.y * 64;
  const int sr = tid & 63, sk = (tid >> 6) * 16;  // A staging: row, k-base

  float acc[4][4] = {};
  float4 a0, a1, a2, a3;

  // stage W chunk kc into Ws[bi] (16KB = 4 x 16B per thread, linear dest)
  auto stageW = [&](int bi, int kc) {
#pragma unroll
    for (int i = 0; i < 4; ++i) {
      const int D = i * 4096 + tid * 16;   // byte offset in tile
      const int kk = D >> 8;               // k row (256B per row)
      const int cb = D & 255;              // byte within row
      const float* src = &Wq[(size_t)(kc * 64 + kk) * KD + c0 + (cb >> 2)];
      __builtin_amdgcn_global_load_lds(
          (const __attribute__((address_space(1))) unsigned int*)src,
          (__attribute__((address_space(3))) unsigned int*)((char*)&Ws[bi][0][0] + D),
          16, 0, 0);
    }
  };

  // prologue: A chunk 0 -> regs -> LDS (transposed), W chunk 0 -> LDS
  stageW(0, 0);
  {
    const float* src = &ph[(size_t)(r0 + sr) * Q_ + sk];
    a0 = *reinterpret_cast<const float4*>(src + 0);
    a1 = *reinterpret_cast<const float4*>(src + 4);
    a2 = *reinterpret_cast<const float4*>(src + 8);
    a3 = *reinterpret_cast<const float4*>(src + 12);
    As[0][sk + 0][sr] = a0.x; As[0][sk + 1][sr] = a0.y;
    As[0][sk + 2][sr] = a0.z; As[0][sk + 3][sr] = a0.w;
    As[0][sk + 4][sr] = a1.x; As[0][sk + 5][sr] = a1.y;
    As[0][sk + 6][sr] = a1.z; As[0][sk + 7][sr] = a1.w;
    As[0][sk + 8][sr] = a2.x; As[0][sk + 9][sr] = a2.y;
    As[0][sk + 10][sr] = a2.z; As[0][sk + 11][sr] = a2.w;
    As[0][sk + 12][sr] = a3.x; As[0][sk + 13][sr] = a3.y;
    As[0][sk + 14][sr] = a3.z; As[0][sk + 15][sr] = a3.w;
  }
  __syncthreads();

  int buf = 0;
  for (int kc = 0; kc < 16; ++kc) {
    if (kc < 15) {  // issue next A loads + W gll early; compute hides latency
      const float* src = &ph[(size_t)(r0 + sr) * Q_ + (kc + 1) * 64 + sk];
      a0 = *reinterpret_cast<const float4*>(src + 0);
      a1 = *reinterpret_cast<const float4*>(src + 4);
      a2 = *reinterpret_cast<const float4*>(src + 8);
      a3 = *reinterpret_cast<const float4*>(src + 12);
      stageW(buf ^ 1, kc + 1);
    }
#pragma unroll 16
    for (int k = 0; k < 64; ++k) {
      const float4 a = *reinterpret_cast<const float4*>(&As[buf][k][ty * 4]);
      const float4 b = *reinterpret_cast<const float4*>(&Ws[buf][k][tx * 4]);
      acc[0][0] = fmaf(a.x, b.x, acc[0][0]); acc[0][1] = fmaf(a.x, b.y, acc[0][1]);
      acc[0][2] = fmaf(a.x, b.z, acc[0][2]); acc[0][3] = fmaf(a.x, b.w, acc[0][3]);
      acc[1][0] = fmaf(a.y, b.x, acc[1][0]); acc[1][1] = fmaf(a.y, b.y, acc[1][1]);
      acc[1][2] = fmaf(a.y, b.z, acc[1][2]); acc[1][3] = fmaf(a.y, b.w, acc[1][3]);
      acc[2][0] = fmaf(a.z, b.x, acc[2][0]); acc[2][1] = fmaf(a.z, b.y, acc[2][1]);
      acc[2][2] = fmaf(a.z, b.z, acc[2][2]); acc[2][3] = fmaf(a.z, b.w, acc[2][3]);
      acc[3][0] = fmaf(a.w, b.x, acc[3][0]); acc[3][1] = fmaf(a.w, b.y, acc[3][1]);
      acc[3][2] = fmaf(a.w, b.z, acc[3][2]); acc[3][3] = fmaf(a.w, b.w, acc[3][3]);
    }
    if (kc < 15) {  // buf^1 fully consumed at the PREVIOUS barrier -> safe
      As[buf ^ 1][sk + 0][sr] = a0.x; As[buf ^ 1][sk + 1][sr] = a0.y;
      As[buf ^ 1][sk + 2][sr] = a0.z; As[buf ^ 1][sk + 3][sr] = a0.w;
      As[buf ^ 1][sk + 4][sr] = a1.x; As[buf ^ 1][sk + 5][sr] = a1.y;
      As[buf ^ 1][sk + 6][sr] = a1.z; As[buf ^ 1][sk + 7][sr] = a1.w;
      As[buf ^ 1][sk + 8][sr] = a2.x; As[buf ^ 1][sk + 9][sr] = a2.y;
      As[buf ^ 1][sk + 10][sr] = a2.z; As[buf ^ 1][sk + 11][sr] = a2.w;
      As[buf ^ 1][sk + 12][sr] = a3.x; As[buf ^ 1][sk + 13][sr] = a3.y;
      As[buf ^ 1][sk + 14][sr] = a3.z; As[buf ^ 1][sk + 15][sr] = a3.w;
    }
    __syncthreads();
    buf ^= 1;
  }

#pragma unroll
  for (int i = 0; i < 4; ++i) {
    const int r = r0 + ty * 4 + i;
    const int c = c0 + tx * 4;
    float4 v;
    v.x = acc[i][0] + bq[c + 0]; v.y = acc[i][1] + bq[c + 1];
    v.z = acc[i][2] + bq[c + 2]; v.w = acc[i][3] + bq[c + 3];
    *reinterpret_cast<float4*>(&q[(size_t)r * KD + c]) = v;
    ushort4 bv;
    bv.x = f2bf(v.x); bv.y = f2bf(v.y); bv.z = f2bf(v.z); bv.w = f2bf(v.w);
    *reinterpret_cast<ushort4*>(&qbf[(size_t)r * KD + c]) = bv;
  }
}

// ---------------------------------------------------------------------------
// k_scores_mfma: 32x32x16 MFMA + branchless packed top-3 per lane, PLUS
// interleaved zeroing of this block's 256KB slice of the alpha output
// (hides the 268MB fill under compute; HBM is ~1% busy here otherwise).
// Block (bc,br): rows [br*64,+64) x cols [bc*1024,+1024).
// ---------------------------------------------------------------------------
__global__ __launch_bounds__(256, 3)
void k_scores_mfma(const unsigned short* __restrict__ qbf,
                   const unsigned short* __restrict__ kbf,
                   unsigned* __restrict__ candP, float* __restrict__ outAlpha) {
  __shared__ __align__(16) char lds[32768];   // 2 x 16KB key tiles (64c x 128k)
  __shared__ unsigned mbuf[64 * 12];
  const int tid = threadIdx.x;
  const int wave = tid >> 6, lane = tid & 63;
  const int l31 = lane & 31, lhi = lane >> 5;
  const int rh = wave >> 1, ch = wave & 1;
  const int bc = blockIdx.x, br = blockIdx.y;
  const int row0 = br * 64;
  const int m_row = row0 + rh * 32 + l31;

  // alpha-zero slice for this block: 256KB = 32 phases x 2 float4-stores/thread
  float4* zb = reinterpret_cast<float4*>(
      (char*)outAlpha + (size_t)(br * 16 + bc) * 262144);
  const float4 z4 = {0.f, 0.f, 0.f, 0.f};

  // ---- q fragments (B-operand): qf[kt] = qbf[m_row][kt*16 + lhi*8 ..+8)
  bhalf8 qf[16];
#pragma unroll
  for (int kt = 0; kt < 16; ++kt)
    qf[kt] = *reinterpret_cast<const bhalf8*>(&qbf[(size_t)m_row * KD + kt * 16 + lhi * 8]);

  auto stage = [&](int bi, int u) {
    const int t = u >> 1, kh = u & 1;
#pragma unroll
    for (int i = 0; i < 4; ++i) {
      const int D = i * 4096 + tid * 16;
      const int colt = D >> 8;                 // 0..63
      const int kb = D & 255;
      const int kbs = kb ^ ((colt & 15) << 4);
      const char* src = (const char*)kbf +
          ((size_t)(bc * 1024 + t * 64 + colt) * 512 + kh * 256 + kbs);
      __builtin_amdgcn_global_load_lds(
          (const __attribute__((address_space(1))) unsigned int*)src,
          (__attribute__((address_space(3))) unsigned int*)(lds + bi * 16384 + D),
          16, 0, 0);
    }
  };

  unsigned P1 = 0u, P2 = 0u, P3 = 0u;   // packed top-3, descending
  const int acol = ch * 32 + l31;       // col within 64-col tile (A-operand row)
  const int swz = (acol & 15) << 4;
  const int kofs = lhi * 16;            // A k-offset bytes (8 bf16)

  stage(0, 0);
  __syncthreads();

  int buf = 0;
  for (int t = 0; t < 16; ++t) {
    f32x16 acc = {};
#pragma unroll
    for (int kh = 0; kh < 2; ++kh) {
      const int u = t * 2 + kh;
      if (u < 31) stage(buf ^ 1, u + 1);
      // interleaved alpha zeroing: 2 stores/thread/phase, drains at barrier
      zb[u * 512 + tid] = z4;
      zb[u * 512 + 256 + tid] = z4;
      const char* kb = lds + buf * 16384 + acol * 256;
#pragma unroll
      for (int kt = 0; kt < 8; ++kt) {
        const bhalf8 af = *reinterpret_cast<const bhalf8*>(kb + ((kt * 32 + kofs) ^ swz));
        acc = __builtin_amdgcn_mfma_f32_32x32x16_bf16(af, qf[kh * 8 + kt], acc, 0, 0, 0);
      }
      if (kh == 1) {
        // fold 16 cols of this row into packed top-3 (branchless)
        const int cb = t * 64 + ch * 32 + lhi * 4;
#pragma unroll
        for (int r = 0; r < 16; ++r) {
          const int rofs = (r & 3) + 8 * (r >> 2);
          const unsigned p =
              (__builtin_bit_cast(unsigned, acc[r] + 512.f) & 0xFFFFF800u) |
              (unsigned)(cb + rofs);
          const unsigned w1 = uminu(P1, p); P1 = umaxu(P1, p);
          const unsigned w2 = uminu(P2, w1); P2 = umaxu(P2, w1);
          P3 = umaxu(P3, w2);
        }
      }
      __syncthreads();   // prefetch tile ready (vmcnt drain) + safe to overwrite
      buf ^= 1;
    }
  }

  // ---- block merge: per row 4 slots x 3 -> top-4 -> global candP
  {
    const int mrow = rh * 32 + l31;
    const int slot = ch * 2 + lhi;
    mbuf[mrow * 12 + slot * 3 + 0] = P1;
    mbuf[mrow * 12 + slot * 3 + 1] = P2;
    mbuf[mrow * 12 + slot * 3 + 2] = P3;
  }
  __syncthreads();
  if (tid < 64) {
    unsigned T1 = 0u, T2 = 0u, T3 = 0u, T4 = 0u;
#pragma unroll
    for (int j = 0; j < 12; ++j) {
      const unsigned p = mbuf[tid * 12 + j];
      const unsigned w1 = uminu(T1, p); T1 = umaxu(T1, p);
      const unsigned w2 = uminu(T2, w1); T2 = umaxu(T2, w1);
      const unsigned w3 = uminu(T3, w2); T3 = umaxu(T3, w2);
      T4 = umaxu(T4, w3);
    }
    const size_t o = (size_t)(row0 + tid) * 64 + bc * 4;
    candP[o + 0] = T1; candP[o + 1] = T2; candP[o + 2] = T3; candP[o + 3] = T4;
  }
}

// ---------------------------------------------------------------------------
// k_finalize: one block per row (alpha row already zeroed by k_scores_mfma).
// Top-8 of 64 packed candidates, exact fp32 rescore, top-2 -> softmax ->
// scatter alpha + emb mix * sigmoid(ph·Wb+bb).
// ---------------------------------------------------------------------------
__global__ __launch_bounds__(256)
void k_finalize(const float* __restrict__ q, const float* __restrict__ keys,
                const float* __restrict__ ph, const float* __restrict__ Wb,
                const float* __restrict__ bb, const float* __restrict__ embs,
                const unsigned* __restrict__ candP,
                float* __restrict__ outEmb, float* __restrict__ outAlpha) {
  __shared__ float red[4];
  __shared__ int   topIdx[8];
  __shared__ float resc[8];
  __shared__ float sParam[3];  // a1, a2, beta
  __shared__ int   sIdx[2];
  const int tid = threadIdx.x;
  const int wave = tid >> 6, lane = tid & 63;
  const int row = blockIdx.x;
  float* arow = outAlpha + (size_t)row * N_;

  // Phase B: beta partial sums.
  {
    const float4 a = *reinterpret_cast<const float4*>(&ph[(size_t)row * Q_ + tid * 4]);
    const float4 w = *reinterpret_cast<const float4*>(&Wb[tid * 4]);
    float s = a.x * w.x + a.y * w.y + a.z * w.z + a.w * w.w;
#pragma unroll
    for (int m = 32; m >= 1; m >>= 1) s += __shfl_xor(s, m);
    if (lane == 0) red[wave] = s;
  }

  // Phase C (wave 0): top-8 of 64 packed candidates by repeated wave-max.
  if (wave == 0) {
    unsigned p = candP[(size_t)row * 64 + lane];
    const int mycol = (lane >> 2) * 1024 + (int)(p & 0x7FFu);
#pragma unroll
    for (int it = 0; it < 8; ++it) {
      unsigned mx = p;
#pragma unroll
      for (int m = 32; m >= 1; m >>= 1) {
        const unsigned o = (unsigned)__shfl_xor((int)mx, m);
        mx = mx > o ? mx : o;
      }
      const unsigned long long bal = __ballot(p == mx);
      const int src = __ffsll((unsigned long long)bal) - 1;
      if (lane == src) { topIdx[it] = mycol; p = 0u; }
    }
  }
  __syncthreads();

  // Phase D: exact fp32 rescore of the 8 candidates; wave w does 2.
  {
#pragma unroll
    for (int h = 0; h < 2; ++h) {
      const int cnd = topIdx[wave * 2 + h];
      const float4 qv = *reinterpret_cast<const float4*>(&q[(size_t)row * KD + lane * 4]);
      const float4 kv = *reinterpret_cast<const float4*>(&keys[(size_t)cnd * KD + lane * 4]);
      float s = qv.x * kv.x + qv.y * kv.y + qv.z * kv.z + qv.w * kv.w;
#pragma unroll
      for (int m = 32; m >= 1; m >>= 1) s += __shfl_xor(s, m);
      if (lane == 0) resc[wave * 2 + h] = s * 0.0625f;
    }
  }
  __syncthreads();

  // Phase E (thread 0): top-2 of rescored (tie -> lower index), softmax, beta.
  if (tid == 0) {
    float w1 = -INFINITY, w2 = -INFINITY; int j1 = 0x7fffffff, j2 = 0x7fffffff;
#pragma unroll
    for (int c = 0; c < 8; ++c) {
      const float v = resc[c]; const int x = topIdx[c];
      const bool beat1 = (v > w1) || (v == w1 && x < j1);
      const bool beat2 = (v > w2) || (v == w2 && x < j2);
      if (beat1) { w2 = w1; j2 = j1; w1 = v; j1 = x; }
      else if (beat2) { w2 = v; j2 = x; }
    }
    const float t = expf(w2 - w1);
    const float inv = 1.f / (1.f + t);
    const float bsum = red[0] + red[1] + red[2] + red[3] + bb[0];
    sParam[0] = inv; sParam[1] = t * inv;
    sParam[2] = 1.f / (1.f + expf(-bsum));
    sIdx[0] = j1; sIdx[1] = j2;
  }
  __syncthreads();

  // Phase F: scatter alpha and emb mix.
  const float a1 = sParam[0], a2 = sParam[1], beta = sParam[2];
  const int j1 = sIdx[0], j2 = sIdx[1];
  if (tid == 0) { arow[j1] = a1; arow[j2] = a2; }
  if (tid < 128) {
    const int f = tid * 4;
    const float4 e1 = *reinterpret_cast<const float4*>(&embs[(size_t)j1 * F_ + f]);
    const float4 e2 = *reinterpret_cast<const float4*>(&embs[(size_t)j2 * F_ + f]);
    float4 o;
    o.x = beta * (a1 * e1.x + a2 * e2.x);
    o.y = beta * (a1 * e1.y + a2 * e2.y);
    o.z = beta * (a1 * e1.z + a2 * e2.z);
    o.w = beta * (a1 * e1.w + a2 * e2.w);
    *reinterpret_cast<float4*>(&outEmb[(size_t)row * F_ + f]) = o;
  }
}

// ---------------------------------------------------------------------------
extern "C" void kernel_launch(void* const* d_in, const int* in_sizes, int n_in,
                              void* d_out, int out_size, void* d_ws, size_t ws_size,
                              hipStream_t stream) {
  const float* ph   = (const float*)d_in[0];
  const float* keys = (const float*)d_in[1];
  const float* embs = (const float*)d_in[2];
  const float* Wq   = (const float*)d_in[3];
  const float* bq   = (const float*)d_in[4];
  const float* Wb   = (const float*)d_in[5];
  const float* bb   = (const float*)d_in[6];

  float* outEmb   = (float*)d_out;
  float* outAlpha = outEmb + (size_t)B_ * F_;

  // workspace (~15 MB)
  float*          q     = (float*)d_ws;                             // 4MB
  unsigned short* qbf   = (unsigned short*)(q + (size_t)B_ * KD);   // 2MB
  unsigned short* kbf   = qbf + (size_t)B_ * KD;                    // 8MB
  unsigned*       candP = (unsigned*)(kbf + (size_t)N_ * KD);       // 1MB

  k_convert_keys<<<(N_ * KD / 8) / 256, 256, 0, stream>>>(keys, kbf);
  k_qproj<<<dim3(KD / 64, B_ / 64), 256, 0, stream>>>(ph, Wq, bq, q, qbf);
  k_scores_mfma<<<dim3(16, 64), 256, 0, stream>>>(qbf, kbf, candP, outAlpha);
  k_finalize<<<B_, 256, 0, stream>>>(q, keys, ph, Wb, bb, embs, candP,
                                     outEmb, outAlpha);
}